// Round 5
// baseline (432.658 us; speedup 1.0000x reference)
//
#include <hip/hip_runtime.h>
#include <hip/hip_bf16.h>
#include <stdint.h>

#define NROWS 32768
#define HDIM  1024
#define CNB   8
#define DCS   128
#define KCB   512
#define ROWS_PB 128

typedef short bf16x8 __attribute__((ext_vector_type(8)));
typedef float f32x4 __attribute__((ext_vector_type(4)));

__device__ __forceinline__ unsigned f2bfu(float x) {
  union { float f; unsigned u; } v; v.f = x;
  return (v.u + 0x7fffu + ((v.u >> 16) & 1u)) >> 16;
}
__device__ __forceinline__ float bfu2f(unsigned short b) {
  union { unsigned u; float f; } v; v.u = ((unsigned)b) << 16;
  return v.f;
}
__device__ __forceinline__ void gload_lds16(const void* g, void* l) {
  __builtin_amdgcn_global_load_lds(
      (const __attribute__((address_space(1))) uint32_t*)g,
      (__attribute__((address_space(3))) uint32_t*)l, 16, 0, 0);
}

// ---- prep: codesB[c] = bf16 image of codes PRE-SCALED by 1/||code||, XOR-swizzled,
//      laid out for linear global_load_lds (4 chunks x 32KB per codebook).
//      cn2[c][k] = ||code||^2 (for loss + output rescale); zero loss slot.
// image byte for (k,d): (k>>7)*32768 + (k&127)*256 + ((2d) ^ ((k&7)<<4))
__global__ __launch_bounds__(256) void prep_kernel(
    const float* __restrict__ codes, unsigned short* __restrict__ codesB,
    float* __restrict__ cn2, float* __restrict__ loss_slot) {
  const int c = blockIdx.y;
  const int k0 = blockIdx.x * 64;
  const int t = threadIdx.x;
  const int kl = t & 63;
  const int dq = t >> 6;
  const int k = k0 + kl;
  const float* src = codes + (size_t)c * DCS * KCB + k;
  float vbuf[32];
  float acc = 0.f;
#pragma unroll
  for (int i = 0; i < 32; ++i) {
    float v = src[(size_t)(dq * 32 + i) * KCB];
    vbuf[i] = v;
    acc += v * v;
  }
  __shared__ float red[256];
  red[t] = acc;
  __syncthreads();
  const float s = red[kl] + red[kl + 64] + red[kl + 128] + red[kl + 192];
  const float rn = rsqrtf(s);
  if (t < 64) cn2[c * KCB + k0 + t] = s;

  char* dstbase = (char*)codesB + (size_t)c * 131072 + (size_t)(k >> 7) * 32768 + (k & 127) * 256;
  const unsigned swzk = (unsigned)(k & 7) << 4;
#pragma unroll
  for (int g = 0; g < 4; ++g) {
    unsigned short pk[8];
#pragma unroll
    for (int j = 0; j < 8; ++j) pk[j] = (unsigned short)f2bfu(vbuf[g * 8 + j] * rn);
    unsigned d2 = (unsigned)((dq * 32 + g * 8) * 2);
    *(uint4*)(dstbase + (d2 ^ swzk)) = *(const uint4*)pk;
  }
  if (blockIdx.x == 0 && c == 0 && t == 0) *loss_slot = 0.f;
}

// ---- main: 128 rows x 1 codebook per block; 8 waves x 16 rows.
// Double-buffered LDS chunks; per-chunk gumbel prefetched to regs under MFMA.
__global__ __launch_bounds__(512, 4) void vq_kernel(
    const float* __restrict__ hidden, const float* __restrict__ gumbel,
    const unsigned short* __restrict__ codesB, const float* __restrict__ cn2g,
    float* __restrict__ out, float* __restrict__ loss_slot) {
  const int c = blockIdx.y;
  const int nb = blockIdx.x * ROWS_PB;
  const int tid = threadIdx.x;
  const int w = tid >> 6;
  const int l = tid & 63;
  const int l15 = l & 15;
  const int l4 = l >> 4;

  __shared__ char ldsB[2 * 32768];   // 2 x 32KB chunk: [k_local 128][d 128] bf16, XOR-swizzled
  __shared__ float wloss[8];

  const char* cbase = (const char*)codesB + (size_t)c * 131072;

#define STAGE(chunk) { \
    const char* _s = cbase + (size_t)(chunk) * 32768; \
    char* _d = ldsB + ((chunk) & 1) * 32768 + w * 1024; \
    gload_lds16(_s + 0 * 8192 + tid * 16, _d + 0 * 8192); \
    gload_lds16(_s + 1 * 8192 + tid * 16, _d + 1 * 8192); \
    gload_lds16(_s + 2 * 8192 + tid * 16, _d + 2 * 8192); \
    gload_lds16(_s + 3 * 8192 + tid * 16, _d + 3 * 8192); }

  // --- h rows first (so their vmcnt wait doesn't drain the stages)
  const int nrow = nb + w * 16 + l15;
  const float* hp = hidden + (size_t)nrow * HDIM + c * DCS + l4 * 8;
  f32x4 hr[4][2];
#pragma unroll
  for (int s = 0; s < 4; ++s) {
    hr[s][0] = __builtin_nontemporal_load((const f32x4*)(hp + s * 32));
    hr[s][1] = __builtin_nontemporal_load((const f32x4*)(hp + s * 32 + 4));
  }

  // prologue stage of chunks 0,1 (latency hidden under norm/cast below)
  STAGE(0)
  STAGE(1)

  float hn2 = 0.f;
  float hv[4][8];
#pragma unroll
  for (int s = 0; s < 4; ++s)
#pragma unroll
    for (int j = 0; j < 4; ++j) {
      hv[s][j] = hr[s][0][j]; hv[s][4 + j] = hr[s][1][j];
    }
#pragma unroll
  for (int s = 0; s < 4; ++s)
#pragma unroll
    for (int j = 0; j < 8; ++j) hn2 += hv[s][j] * hv[s][j];
  hn2 += __shfl_xor(hn2, 16);
  hn2 += __shfl_xor(hn2, 32);
  const float hnorm = sqrtf(hn2);
  const float rh = hnorm > 0.f ? 1.0f / hnorm : 0.f;
  bf16x8 afr[4];
#pragma unroll
  for (int s = 0; s < 4; ++s)
#pragma unroll
    for (int j = 0; j < 8; ++j) afr[s][j] = (short)f2bfu(hv[s][j] * rh);

  const float* gbase = gumbel + ((size_t)nrow * CNB + c) * KCB + l4 * 4;
  const unsigned swz = (unsigned)(l15 & 7) << 4;

  float bs = -3.4e38f, ba = 0.f;
  int bk = 0;

  __syncthreads();   // chunks 0,1 staged (vmcnt drain)

#pragma unroll
  for (int i = 0; i < 4; ++i) {
    const int kc = i * 128;
    const char* buf = ldsB + (i & 1) * 32768;

    // --- gumbel prefetch for THIS chunk; latency hides under the MFMA phase
    f32x4 garr[8];
#pragma unroll
    for (int t = 0; t < 8; ++t)
      garr[t] = __builtin_nontemporal_load((const f32x4*)(gbase + kc + t * 16));

    // --- MFMA over current chunk
    f32x4 acc[8];
#pragma unroll
    for (int t = 0; t < 8; ++t) acc[t] = (f32x4){0.f, 0.f, 0.f, 0.f};
#pragma unroll
    for (int t = 0; t < 8; ++t) {
      const unsigned rowbase = (unsigned)((t * 16 + l15) * 256);
#pragma unroll
      for (int s = 0; s < 4; ++s) {
        bf16x8 bfr = *(const bf16x8*)(buf + rowbase + (((unsigned)(s * 64 + l4 * 16)) ^ swz));
        acc[t] = __builtin_amdgcn_mfma_f32_16x16x32_bf16(bfr, afr[s], acc[t], 0, 0, 0);
      }
    }

    // --- scores + per-lane argmax (codes pre-scaled: sc = cos + g)
#pragma unroll
    for (int t = 0; t < 8; ++t) {
#pragma unroll
      for (int r = 0; r < 4; ++r) {
        const int kf = kc + t * 16 + l4 * 4 + r;
        float sc = acc[t][r] + garr[t][r];
        if (sc > bs) { bs = sc; bk = kf; ba = acc[t][r]; }
      }
    }

    __syncthreads();   // all waves done reading buf[i&1]; stage(i+1) (1 iter old) drained
    if (i < 2) STAGE(i + 2)   // overwrite just-freed buffer; completes during next phase
  }

  // --- cross-lane argmax over the 4 l4 replicas of each h-row
#pragma unroll
  for (int m = 16; m <= 32; m <<= 1) {
    float os = __shfl_xor(bs, m);
    int ok = __shfl_xor(bk, m);
    float oa = __shfl_xor(ba, m);
    if (os > bs || (os == bs && ok < bk)) { bs = os; bk = ok; ba = oa; }
  }

  // --- epilogue: nh = bf16(c/||c||) * ||c||; loss via ||c||^2+||h||^2-2*cos*||h||*||c||
  const float c2 = cn2g[c * KCB + bk];
  const float cn = sqrtf(c2);
  const float arg = c2 + hn2 - 2.f * (ba * hnorm * cn);
  float lsum = (l4 == 0) ? sqrtf(fmaxf(arg, 0.f)) : 0.f;

  const char* cb = cbase + (size_t)(bk >> 7) * 32768 + (bk & 127) * 256;
  const unsigned swzk = (unsigned)(bk & 7) << 4;
  float* op = out + (size_t)nrow * HDIM + c * DCS + l4 * 32;
#pragma unroll
  for (int j = 0; j < 4; ++j) {
    unsigned d2 = (unsigned)((l4 * 32 + j * 8) * 2);
    bf16x8 cv = *(const bf16x8*)(cb + (d2 ^ swzk));
    f32x4 o0, o1;
#pragma unroll
    for (int e = 0; e < 4; ++e) {
      o0[e] = bfu2f((unsigned short)cv[e]) * cn;
      o1[e] = bfu2f((unsigned short)cv[4 + e]) * cn;
    }
    __builtin_nontemporal_store(o0, (f32x4*)(op + j * 8));
    __builtin_nontemporal_store(o1, (f32x4*)(op + j * 8 + 4));
  }

#pragma unroll
  for (int m = 1; m <= 32; m <<= 1) lsum += __shfl_xor(lsum, m);
  if (l == 0) wloss[w] = lsum;
  __syncthreads();
  if (tid == 0) {
    float tot = 0.f;
#pragma unroll
    for (int i = 0; i < 8; ++i) tot += wloss[i];
    atomicAdd(loss_slot, tot * 1.2f);
  }
#undef STAGE
}

extern "C" void kernel_launch(void* const* d_in, const int* in_sizes, int n_in,
                              void* d_out, int out_size, void* d_ws, size_t ws_size,
                              hipStream_t stream) {
  const float* hidden = (const float*)d_in[0];
  const float* codes  = (const float*)d_in[1];
  const float* gumbel = (const float*)d_in[2];
  float* out = (float*)d_out;
  unsigned short* codesB = (unsigned short*)d_ws;              // 1 MB (8 x 128KB images)
  float* cn2 = (float*)((char*)d_ws + (size_t)CNB * 131072);   // 16 KB
  float* loss_slot = out + (size_t)NROWS * HDIM;

  prep_kernel<<<dim3(8, CNB), 256, 0, stream>>>(codes, codesB, cn2, loss_slot);
  vq_kernel<<<dim3(NROWS / ROWS_PB, CNB), 512, 0, stream>>>(hidden, gumbel, codesB, cn2, out, loss_slot);
}

// Round 6
// 213.743 us; speedup vs baseline: 2.0242x; 2.0242x over previous
//
#include <hip/hip_runtime.h>
#include <hip/hip_bf16.h>
#include <stdint.h>

#define NROWS 32768
#define HDIM  1024
#define CNB   8
#define DCS   128
#define KCB   512
#define ROWS_PB 128

typedef short bf16x8 __attribute__((ext_vector_type(8)));
typedef float f32x4 __attribute__((ext_vector_type(4)));

__device__ __forceinline__ unsigned f2bfu(float x) {
  union { float f; unsigned u; } v; v.f = x;
  return (v.u + 0x7fffu + ((v.u >> 16) & 1u)) >> 16;
}
__device__ __forceinline__ float bfu2f(unsigned short b) {
  union { unsigned u; float f; } v; v.u = ((unsigned)b) << 16;
  return v.f;
}
__device__ __forceinline__ void gload_lds16(const void* g, void* l) {
  __builtin_amdgcn_global_load_lds(
      (const __attribute__((address_space(1))) uint32_t*)g,
      (__attribute__((address_space(3))) uint32_t*)l, 16, 0, 0);
}

// ---- prep: codesB[c] = bf16 image of codes PRE-SCALED by 1/||code||, XOR-swizzled,
//      laid out for linear global_load_lds (4 chunks x 32KB per codebook).
//      cn2[c][k] = ||code||^2 (for loss + output rescale); zero loss slot.
// image byte for (k,d): (k>>7)*32768 + (k&127)*256 + ((2d) ^ ((k&7)<<4))
__global__ __launch_bounds__(256) void prep_kernel(
    const float* __restrict__ codes, unsigned short* __restrict__ codesB,
    float* __restrict__ cn2, float* __restrict__ loss_slot) {
  const int c = blockIdx.y;
  const int k0 = blockIdx.x * 64;
  const int t = threadIdx.x;
  const int kl = t & 63;
  const int dq = t >> 6;
  const int k = k0 + kl;
  const float* src = codes + (size_t)c * DCS * KCB + k;
  float vbuf[32];
  float acc = 0.f;
#pragma unroll
  for (int i = 0; i < 32; ++i) {
    float v = src[(size_t)(dq * 32 + i) * KCB];
    vbuf[i] = v;
    acc += v * v;
  }
  __shared__ float red[256];
  red[t] = acc;
  __syncthreads();
  const float s = red[kl] + red[kl + 64] + red[kl + 128] + red[kl + 192];
  const float rn = rsqrtf(s);
  if (t < 64) cn2[c * KCB + k0 + t] = s;

  char* dstbase = (char*)codesB + (size_t)c * 131072 + (size_t)(k >> 7) * 32768 + (k & 127) * 256;
  const unsigned swzk = (unsigned)(k & 7) << 4;
#pragma unroll
  for (int g = 0; g < 4; ++g) {
    unsigned short pk[8];
#pragma unroll
    for (int j = 0; j < 8; ++j) pk[j] = (unsigned short)f2bfu(vbuf[g * 8 + j] * rn);
    unsigned d2 = (unsigned)((dq * 32 + g * 8) * 2);
    *(uint4*)(dstbase + (d2 ^ swzk)) = *(const uint4*)pk;
  }
  if (blockIdx.x == 0 && c == 0 && t == 0) *loss_slot = 0.f;
}

// ---- main: 128 rows x 1 codebook per block; 8 waves x 16 rows.
// Double-buffered LDS chunks; per-chunk gumbel prefetched to regs under MFMA.
__global__ __launch_bounds__(512, 4) void vq_kernel(
    const float* __restrict__ hidden, const float* __restrict__ gumbel,
    const unsigned short* __restrict__ codesB, const float* __restrict__ cn2g,
    float* __restrict__ out, float* __restrict__ loss_slot) {
  const int c = blockIdx.y;
  const int nb = blockIdx.x * ROWS_PB;
  const int tid = threadIdx.x;
  const int w = tid >> 6;
  const int l = tid & 63;
  const int l15 = l & 15;
  const int l4 = l >> 4;

  __shared__ char ldsB[2 * 32768];   // 2 x 32KB chunk: [k_local 128][d 128] bf16, XOR-swizzled
  __shared__ float wloss[8];

  const char* cbase = (const char*)codesB + (size_t)c * 131072;

#define STAGE(chunk) { \
    const char* _s = cbase + (size_t)(chunk) * 32768; \
    char* _d = ldsB + ((chunk) & 1) * 32768 + w * 1024; \
    gload_lds16(_s + 0 * 8192 + tid * 16, _d + 0 * 8192); \
    gload_lds16(_s + 1 * 8192 + tid * 16, _d + 1 * 8192); \
    gload_lds16(_s + 2 * 8192 + tid * 16, _d + 2 * 8192); \
    gload_lds16(_s + 3 * 8192 + tid * 16, _d + 3 * 8192); }

  // --- h rows first (so their vmcnt wait doesn't drain the stages)
  const int nrow = nb + w * 16 + l15;
  const float* hp = hidden + (size_t)nrow * HDIM + c * DCS + l4 * 8;
  f32x4 hr[4][2];
#pragma unroll
  for (int s = 0; s < 4; ++s) {
    hr[s][0] = *(const f32x4*)(hp + s * 32);
    hr[s][1] = *(const f32x4*)(hp + s * 32 + 4);
  }

  // prologue stage of chunks 0,1 (latency hidden under norm/cast below)
  STAGE(0)
  STAGE(1)

  float hn2 = 0.f;
  float hv[4][8];
#pragma unroll
  for (int s = 0; s < 4; ++s)
#pragma unroll
    for (int j = 0; j < 4; ++j) {
      hv[s][j] = hr[s][0][j]; hv[s][4 + j] = hr[s][1][j];
    }
#pragma unroll
  for (int s = 0; s < 4; ++s)
#pragma unroll
    for (int j = 0; j < 8; ++j) hn2 += hv[s][j] * hv[s][j];
  hn2 += __shfl_xor(hn2, 16);
  hn2 += __shfl_xor(hn2, 32);
  const float hnorm = sqrtf(hn2);
  const float rh = hnorm > 0.f ? 1.0f / hnorm : 0.f;
  bf16x8 afr[4];
#pragma unroll
  for (int s = 0; s < 4; ++s)
#pragma unroll
    for (int j = 0; j < 8; ++j) afr[s][j] = (short)f2bfu(hv[s][j] * rh);

  const float* gbase = gumbel + ((size_t)nrow * CNB + c) * KCB + l4 * 4;
  const unsigned swz = (unsigned)(l15 & 7) << 4;

  float bs = -3.4e38f, ba = 0.f;
  int bk = 0;

  __syncthreads();   // chunks 0,1 staged (vmcnt drain)

#pragma unroll
  for (int i = 0; i < 4; ++i) {
    const int kc = i * 128;
    const char* buf = ldsB + (i & 1) * 32768;

    // --- gumbel prefetch for THIS chunk; latency hides under the MFMA phase
    f32x4 garr[8];
#pragma unroll
    for (int t = 0; t < 8; ++t)
      garr[t] = *(const f32x4*)(gbase + kc + t * 16);

    // --- MFMA over current chunk
    f32x4 acc[8];
#pragma unroll
    for (int t = 0; t < 8; ++t) acc[t] = (f32x4){0.f, 0.f, 0.f, 0.f};
#pragma unroll
    for (int t = 0; t < 8; ++t) {
      const unsigned rowbase = (unsigned)((t * 16 + l15) * 256);
#pragma unroll
      for (int s = 0; s < 4; ++s) {
        bf16x8 bfr = *(const bf16x8*)(buf + rowbase + (((unsigned)(s * 64 + l4 * 16)) ^ swz));
        acc[t] = __builtin_amdgcn_mfma_f32_16x16x32_bf16(bfr, afr[s], acc[t], 0, 0, 0);
      }
    }

    // --- scores + per-lane argmax (codes pre-scaled: sc = cos + g)
#pragma unroll
    for (int t = 0; t < 8; ++t) {
#pragma unroll
      for (int r = 0; r < 4; ++r) {
        const int kf = kc + t * 16 + l4 * 4 + r;
        float sc = acc[t][r] + garr[t][r];
        if (sc > bs) { bs = sc; bk = kf; ba = acc[t][r]; }
      }
    }

    __syncthreads();   // all waves done reading buf[i&1]; stage(i+1) (1 iter old) drained
    if (i < 2) STAGE(i + 2)   // overwrite just-freed buffer; completes during next phase
  }

  // --- cross-lane argmax over the 4 l4 replicas of each h-row
#pragma unroll
  for (int m = 16; m <= 32; m <<= 1) {
    float os = __shfl_xor(bs, m);
    int ok = __shfl_xor(bk, m);
    float oa = __shfl_xor(ba, m);
    if (os > bs || (os == bs && ok < bk)) { bs = os; bk = ok; ba = oa; }
  }

  // --- epilogue: nh = bf16(c/||c||) * ||c||; loss via ||c||^2+||h||^2-2*cos*||h||*||c||
  const float c2 = cn2g[c * KCB + bk];
  const float cn = sqrtf(c2);
  const float arg = c2 + hn2 - 2.f * (ba * hnorm * cn);
  float lsum = (l4 == 0) ? sqrtf(fmaxf(arg, 0.f)) : 0.f;

  const char* cb = cbase + (size_t)(bk >> 7) * 32768 + (bk & 127) * 256;
  const unsigned swzk = (unsigned)(bk & 7) << 4;
  float* op = out + (size_t)nrow * HDIM + c * DCS + l4 * 32;
#pragma unroll
  for (int j = 0; j < 4; ++j) {
    unsigned d2 = (unsigned)((l4 * 32 + j * 8) * 2);
    bf16x8 cv = *(const bf16x8*)(cb + (d2 ^ swzk));
    f32x4 o0, o1;
#pragma unroll
    for (int e = 0; e < 4; ++e) {
      o0[e] = bfu2f((unsigned short)cv[e]) * cn;
      o1[e] = bfu2f((unsigned short)cv[4 + e]) * cn;
    }
    *(f32x4*)(op + j * 8) = o0;
    *(f32x4*)(op + j * 8 + 4) = o1;
  }

#pragma unroll
  for (int m = 1; m <= 32; m <<= 1) lsum += __shfl_xor(lsum, m);
  if (l == 0) wloss[w] = lsum;
  __syncthreads();
  if (tid == 0) {
    float tot = 0.f;
#pragma unroll
    for (int i = 0; i < 8; ++i) tot += wloss[i];
    atomicAdd(loss_slot, tot * 1.2f);
  }
#undef STAGE
}

extern "C" void kernel_launch(void* const* d_in, const int* in_sizes, int n_in,
                              void* d_out, int out_size, void* d_ws, size_t ws_size,
                              hipStream_t stream) {
  const float* hidden = (const float*)d_in[0];
  const float* codes  = (const float*)d_in[1];
  const float* gumbel = (const float*)d_in[2];
  float* out = (float*)d_out;
  unsigned short* codesB = (unsigned short*)d_ws;              // 1 MB (8 x 128KB images)
  float* cn2 = (float*)((char*)d_ws + (size_t)CNB * 131072);   // 16 KB
  float* loss_slot = out + (size_t)NROWS * HDIM;

  prep_kernel<<<dim3(8, CNB), 256, 0, stream>>>(codes, codesB, cn2, loss_slot);
  vq_kernel<<<dim3(NROWS / ROWS_PB, CNB), 512, 0, stream>>>(hidden, gumbel, codesB, cn2, out, loss_slot);
}